// Round 18
// baseline (73.880 us; speedup 1.0000x reference)
//
#include <hip/hip_runtime.h>

#define B_   64
#define H_   128
#define W_   2048
#define HW_  (H_ * W_)        // 262144
#define OH_  128
#define OW_  2048

typedef float nfloat4 __attribute__((ext_vector_type(4)));
typedef float f2v __attribute__((ext_vector_type(2), aligned(4)));

// OpenBLAS sgemm emulation — SkylakeX params (VERIFIED bit-exact in round 6):
//   SGEMM_DEFAULT_Q = 320; K = 262144 -> blocks 0..817 len 320,
//   blk 818: off 261760 len 192; blk 819: off 261952 len 192.
//   Per C element: single sequential FMA chain over k within each block;
//   cross-block C += S_blk ascending; + b_loc in fp32.
// !!! The per-(blk,b,j) fmaf sequence and the K2 fp32 replay are bit-locked —
// !!! optimizations may only change load mechanics / parallel mapping.
#define QBLK 320
#define NBLK 820

__device__ __forceinline__ int blk_off(int blk) {
    if (blk <= 818) return blk * QBLK;    // 818*320 = 261760
    return 261952;                        // blk 819
}
__device__ __forceinline__ int blk_len(int blk) {
    return (blk < 818) ? 320 : 192;
}

// ---------------------------------------------------------------------------
// K1 (round-18): MORE, SMALLER BLOCKS for staging continuity.
// r17 diagnosis: ~2 resident blocks/CU issue staging in bursts -> CU has
// loads in flight only ~25% of the time -> 0.85 TB/s. Here: block =
// (kblk, 16-row quarter), 3280 blocks x 128 thr (2 waves), LDS 28.4 KB ->
// 5 blocks/CU -> ~2.5x overlapping staging windows; scheduler pipelines.
//  - x staged via global_load_lds w=16, stride-81 rows (kept from r17).
//    Read side: 4 j-groups read the same 16 rows -> 4-way same-address
//    broadcast + 2 distinct addrs per bank-group = conflict-free.
//  - w transposed in LDS (r17 reg-batch), 4 distinct b128 addrs per wave.
//  - compute: lanes 0..95 = (j = tid>>4, b = tid&15); 96..127 idle (VALU
//    is not the constraint). Chain = exact k-ascending fmaf sequence.
// part layout: [kblk][b*6+j].
// ---------------------------------------------------------------------------
#define XSTR 81
__global__ __launch_bounds__(128)
void st_block_sums(const float* __restrict__ x, const float* __restrict__ w,
                   float* __restrict__ part)
{
    __shared__ float4 xs4[16 * XSTR];    // 20736 B
    __shared__ float  wt[6 * QBLK];      //  7680 B  (28.4 KB total)
    const int task = blockIdx.x;         // 0..3279
    const int kblk = task >> 2;
    const int qtr  = task & 3;
    const int b0   = qtr * 16;
    const int tid  = threadIdx.x;

    const int off = blk_off(kblk);
    const int len = blk_len(kblk);       // 320 or 192
    const int nt4 = len >> 2;            // 80 or 48

    const int widx = tid >> 6;           // wave 0..1
    const int lane = tid & 63;

    // x staging: slot s (< 16*81) holds global unit (s%81 -> clamped) of row
    // b0 + s/81. Wave-uniform LDS dest base + lane*16; per-lane source;
    // EXEC-masked tail. Pad slots (unit 80 / >= nt4) load unit 0: never read.
#pragma unroll
    for (int i = 0; i < 11; ++i) {
        const int base = i * 128 + widx * 64;     // wave-uniform slot base
        if (base < 16 * XSTR) {                   // uniform per wave
            const int idx = base + lane;
            if (idx < 16 * XSTR) {                // EXEC mask (last chunk)
                const int r  = idx / XSTR;
                const int f4 = idx % XSTR;
                const int ug = (f4 < nt4) ? f4 : 0;   // pad -> harmless src
                const float* gp = x + (size_t)(b0 + r) * HW_ + off + ug * 4;
                __builtin_amdgcn_global_load_lds(
                    (const __attribute__((address_space(1))) unsigned int*)gp,
                    (__attribute__((address_space(3))) unsigned int*)&xs4[base],
                    16, 0, 0);
            }
        }
    }

    // w staging: batched regs -> transposed LDS wt[j][k]
    float wreg[15];
#pragma unroll
    for (int i = 0; i < 15; ++i) {
        const int e = tid + i * 128;
        wreg[i] = (e < 6 * len) ? w[(size_t)off * 6 + e] : 0.f;
    }
#pragma unroll
    for (int i = 0; i < 15; ++i) {
        const int e = tid + i * 128;
        if (e < 6 * len) wt[(e % 6) * QBLK + (e / 6)] = wreg[i];
    }
    __syncthreads();   // drains global_load_lds (vmcnt) + ds_writes

    if (tid < 96) {
        const int j = tid >> 4;          // 0..5
        const int b = tid & 15;          // row within quarter

        const float4* __restrict__ xr = xs4 + b * XSTR;
        const float*  __restrict__ wr = wt + j * QBLK;

        float a = 0.f;
        if (nt4 == 80) {
#pragma unroll
            for (int t4 = 0; t4 < 80; ++t4) {
                const float4 xv = xr[t4];                          // bcast-free
                const float4 wv = *(const float4*)(wr + t4 * 4);   // broadcast
                a = fmaf(xv.x, wv.x, a);
                a = fmaf(xv.y, wv.y, a);
                a = fmaf(xv.z, wv.z, a);
                a = fmaf(xv.w, wv.w, a);
            }
        } else {
#pragma unroll
            for (int t4 = 0; t4 < 48; ++t4) {
                const float4 xv = xr[t4];
                const float4 wv = *(const float4*)(wr + t4 * 4);
                a = fmaf(xv.x, wv.x, a);
                a = fmaf(xv.y, wv.y, a);
                a = fmaf(xv.z, wv.z, a);
                a = fmaf(xv.w, wv.w, a);
            }
        }

        part[(size_t)kblk * 384 + (size_t)(b0 + b) * 6 + j] = a;
    }
}

// ---------------------------------------------------------------------------
// K1b (round-17, unchanged): ordered cross-block accumulation, latency-
// batched (64-wide register rounds; add order identical -> bit-exact).
// ---------------------------------------------------------------------------
__global__ __launch_bounds__(64)
void st_theta_final(const float* __restrict__ part, const float* __restrict__ bl,
                    float* __restrict__ theta)
{
#pragma clang fp contract(off)
    const int i = blockIdx.x * 64 + threadIdx.x;   // 0..383
    const int j = i % 6;
    const float* __restrict__ p = part + i;        // stride 384 per kblk

    float acc;
    {
        float r[64];
#pragma unroll
        for (int u = 0; u < 64; ++u) r[u] = p[(size_t)u * 384];
        acc = r[0];
#pragma unroll
        for (int u = 1; u < 64; ++u) acc = acc + r[u];
    }
    for (int base = 64; base < 768; base += 64) {
        float r[64];
#pragma unroll
        for (int u = 0; u < 64; ++u) r[u] = p[(size_t)(base + u) * 384];
#pragma unroll
        for (int u = 0; u < 64; ++u) acc = acc + r[u];
    }
    {
        float r[52];
#pragma unroll
        for (int u = 0; u < 52; ++u) r[u] = p[(size_t)(768 + u) * 384];
#pragma unroll
        for (int u = 0; u < 52; ++u) acc = acc + r[u];
    }
    theta[i] = acc + bl[j];
}

// ---------------------------------------------------------------------------
// K2 (round-16, unchanged): bilinear sampler — faithful fp32 numpy replay.
// Float-domain clip via v_med3_f32; divergence-free float2 loads + cndmask.
// ---------------------------------------------------------------------------
__global__ __launch_bounds__(256)
void st_sample(const float* __restrict__ x, const float* __restrict__ theta,
               float* __restrict__ out)
{
#pragma clang fp contract(off)
    __shared__ float th[6];
    const int blk = blockIdx.x;
    const int b   = blk >> 8;          // 256 blocks per batch
    const int rem = blk & 255;
    const int yo  = rem >> 1;
    const int seg = rem & 1;

    if (threadIdx.x < 6) th[threadIdx.x] = theta[b * 6 + threadIdx.x];
    __syncthreads();

    const float t00 = th[0], t01 = th[1], t02 = th[2];
    const float t10 = th[3], t11 = th[4], t12 = th[5];

    const int xo0 = seg * 1024 + threadIdx.x * 4;
    const float* __restrict__ img = x + (size_t)b * HW_;
    const float yof = (float)yo;

    const float cx1 = t01 * yof;
    const float cy1 = t11 * yof;

    nfloat4 o;
#pragma unroll
    for (int i = 0; i < 4; ++i) {
        const float xof = (float)(xo0 + i);
        const float px  = t00 * xof;
        const float sx  = px + cx1;
        const float xq  = sx + t02;
        const float py  = t10 * xof;
        const float sy  = py + cy1;
        const float yq  = sy + t12;

        const float xf0 = floorf(xq);
        const float yf0 = floorf(yq);

        const float x0f = __builtin_amdgcn_fmed3f(xf0,        0.f, 2047.f);
        const float x1f = __builtin_amdgcn_fmed3f(xf0 + 1.0f, 0.f, 2047.f);
        const float y0f = __builtin_amdgcn_fmed3f(yf0,        0.f,  127.f);
        const float y1f = __builtin_amdgcn_fmed3f(yf0 + 1.0f, 0.f,  127.f);

        const float basef = fminf(x0f, 2046.0f);
        const int base_i = (int)basef;
        const int y0c    = (int)y0f;
        const int y1c    = (int)y1f;

        const f2v v0 = *(const f2v*)(img + y0c * W_ + base_i);
        const f2v v1 = *(const f2v*)(img + y1c * W_ + base_i);

        const bool hiA = (x0f == 2047.0f);   // right clamp
        const bool loC = (x1f == basef);     // left clamp
        const float Ia = hiA ? v0.y : v0.x;
        const float Ic = loC ? v0.x : v0.y;
        const float Ib = hiA ? v1.y : v1.x;
        const float Id = loC ? v1.x : v1.y;

        const float gx = x1f - xq;
        const float fx = xq - x0f;
        const float gy = y1f - yq;
        const float fy = yq - y0f;

        const float wa = gx * gy;
        const float wb = gx * fy;
        const float wc = fx * gy;
        const float wd = fx * fy;

        const float pa = wa * Ia;
        const float pb = wb * Ib;
        const float s1 = pa + pb;
        const float pc = wc * Ic;
        const float s2 = s1 + pc;
        const float pd = wd * Id;
        o[i] = s2 + pd;
    }

    const size_t oidx = ((size_t)b * OH_ + yo) * OW_ + xo0;
    __builtin_nontemporal_store(o, (nfloat4*)(out + oidx));
}

extern "C" void kernel_launch(void* const* d_in, const int* in_sizes, int n_in,
                              void* d_out, int out_size, void* d_ws, size_t ws_size,
                              hipStream_t stream)
{
    const float* x  = (const float*)d_in[0];
    const float* w  = (const float*)d_in[1];
    const float* bl = (const float*)d_in[2];
    float* out = (float*)d_out;

    // d_out doubles as the 1.26 MB block-sum scratch (820*384 floats), fully
    // consumed by st_theta_final before st_sample overwrites every element.
    float* part  = (float*)d_out;
    float* theta = (float*)d_ws;    // 384 floats

    st_block_sums<<<NBLK * 4, 128, 0, stream>>>(x, w, part);
    st_theta_final<<<6, 64, 0, stream>>>(part, bl, theta);
    st_sample<<<B_ * OH_ * 2, 256, 0, stream>>>(x, theta, out);
}

// Round 19
// 69.562 us; speedup vs baseline: 1.0621x; 1.0621x over previous
//
#include <hip/hip_runtime.h>

#define B_   64
#define H_   128
#define W_   2048
#define HW_  (H_ * W_)        // 262144
#define OH_  128
#define OW_  2048

typedef float nfloat4 __attribute__((ext_vector_type(4)));
typedef float f2v __attribute__((ext_vector_type(2), aligned(4)));

// OpenBLAS sgemm emulation — SkylakeX params (VERIFIED bit-exact in round 6):
//   SGEMM_DEFAULT_Q = 320; K = 262144 -> blocks 0..817 len 320,
//   blk 818: off 261760 len 192; blk 819: off 261952 len 192.
//   Per C element: single sequential FMA chain over k within each block;
//   cross-block C += S_blk ascending; + b_loc in fp32.
// !!! The per-(blk,b,j) fmaf sequence and the K2 fp32 replay are bit-locked —
// !!! optimizations may only change load mechanics / parallel mapping.
#define QBLK 320
#define NBLK 820

__device__ __forceinline__ int blk_off(int blk) {
    if (blk <= 818) return blk * QBLK;    // 818*320 = 261760
    return 261952;                        // blk 819
}
__device__ __forceinline__ int blk_len(int blk) {
    return (blk < 818) ? 320 : 192;
}

// ---------------------------------------------------------------------------
// K1 (round-19): r17 geometry + IN-BLOCK DOUBLE-BUFFERED SUB-PANELS.
// r18 falsified "more blocks"; the real issue is stage->drain->compute
// serialization (zero VMEM in flight during compute). Here each kblk is
// split into 2 half-panels; panel s+1's global_load_lds is ISSUED before
// compute(s), so its ~900cy flight hides under ~1700cy of compute, and the
// barrier drain is nearly free. Accumulator carries across panels in exact
// k order -> bit-identical chains.
//   xb stride 41 (== 1 mod 8): bank-group spread, same class as r17's 81.
//   w: reg-batched global load issued with the stage, ds_written after
//   compute (lgkm drained by the same barrier).
// LDS = 2*20992 + 2*3840 = 49.7 KB -> 3 blocks/CU (9 waves/CU).
// part layout: [kblk][b*6+j].
// ---------------------------------------------------------------------------
#define XS2 41
__global__ __launch_bounds__(192)
void st_block_sums(const float* __restrict__ x, const float* __restrict__ w,
                   float* __restrict__ part)
{
    __shared__ float4 xb[2][32 * XS2];   // 2 x 20992 B
    __shared__ float  wb[2][6 * 160];    // 2 x  3840 B  (49.66 KB total)
    const int kblk = blockIdx.x >> 1;
    const int half = blockIdx.x & 1;
    const int tid  = threadIdx.x;

    const int off  = blk_off(kblk);
    const int len  = blk_len(kblk);      // 320 or 192
    const int lenh = len >> 1;           // 160 or 96
    const int nt4h = lenh >> 2;          // 40 or 24
    const int b0   = half * 32;

    const int widx = tid >> 6;           // wave 0..2
    const int lane = tid & 63;

    // x sub-panel staging: slot s*? -> row idx/41, unit idx%41 (pad units
    // clamp to 0: staged but never read). Wave-uniform LDS dest + lane*16.
#define STAGE_X(s)                                                            \
    _Pragma("unroll")                                                         \
    for (int i = 0; i < 7; ++i) {                                             \
        const int base = i * 192 + widx * 64;                                 \
        if (base < 32 * XS2) {                                                \
            const int idx = base + lane;                                      \
            if (idx < 32 * XS2) {                                             \
                const int r  = idx / XS2;                                     \
                const int f4 = idx % XS2;                                     \
                const int ug = (f4 < nt4h) ? f4 : 0;                          \
                const float* gp = x + (size_t)(b0 + r) * HW_ + off            \
                                  + (s) * lenh + ug * 4;                      \
                __builtin_amdgcn_global_load_lds(                             \
                    (const __attribute__((address_space(1))) unsigned int*)gp,\
                    (__attribute__((address_space(3))) unsigned int*)&xb[s][base],\
                    16, 0, 0);                                                \
            }                                                                 \
        }                                                                     \
    }

#define WLOAD(s, rg)                                                          \
    _Pragma("unroll")                                                         \
    for (int i = 0; i < 5; ++i) {                                             \
        const int e = tid + i * 192;                                          \
        rg[i] = (e < 6 * lenh) ? w[((size_t)off + (size_t)(s) * lenh) * 6 + e]\
                               : 0.f;                                         \
    }

#define WSTORE(s, rg)                                                         \
    _Pragma("unroll")                                                         \
    for (int i = 0; i < 5; ++i) {                                             \
        const int e = tid + i * 192;                                          \
        if (e < 6 * lenh) wb[s][(e % 6) * 160 + (e / 6)] = rg[i];             \
    }

#define COMPUTE(xr, wq, N)                                                    \
    _Pragma("unroll")                                                         \
    for (int t4 = 0; t4 < (N); ++t4) {                                        \
        const float4 xv = (xr)[t4];                                           \
        const float4 wv = *(const float4*)((wq) + t4 * 4);                    \
        a = fmaf(xv.x, wv.x, a); a = fmaf(xv.y, wv.y, a);                     \
        a = fmaf(xv.z, wv.z, a); a = fmaf(xv.w, wv.w, a);                     \
    }

    float wr0[5], wr1[5];
    STAGE_X(0)
    WLOAD(0, wr0)
    WSTORE(0, wr0)
    __syncthreads();                 // panel 0 ready (prologue burst)

    const int j = tid >> 5;          // 0..5 (2 j per wave)
    const int b = tid & 31;          // row within half
    const float4* __restrict__ xr0 = &xb[0][b * XS2];
    const float4* __restrict__ xr1 = &xb[1][b * XS2];
    const float*  __restrict__ wq0 = &wb[0][j * 160];
    const float*  __restrict__ wq1 = &wb[1][j * 160];

    float a = 0.f;

    STAGE_X(1)                       // issue NOW: flight overlaps compute(0)
    WLOAD(1, wr1)

    if (nt4h == 40) { COMPUTE(xr0, wq0, 40) }
    else            { COMPUTE(xr0, wq0, 24) }

    WSTORE(1, wr1)
    __syncthreads();                 // panel 1 ready (loads issued ~1700cy ago)

    if (nt4h == 40) { COMPUTE(xr1, wq1, 40) }
    else            { COMPUTE(xr1, wq1, 24) }

    part[(size_t)kblk * 384 + (size_t)(b0 + b) * 6 + j] = a;

#undef STAGE_X
#undef WLOAD
#undef WSTORE
#undef COMPUTE
}

// ---------------------------------------------------------------------------
// K1b (round-17, unchanged): ordered cross-block accumulation, latency-
// batched (64-wide register rounds; add order identical -> bit-exact).
// ---------------------------------------------------------------------------
__global__ __launch_bounds__(64)
void st_theta_final(const float* __restrict__ part, const float* __restrict__ bl,
                    float* __restrict__ theta)
{
#pragma clang fp contract(off)
    const int i = blockIdx.x * 64 + threadIdx.x;   // 0..383
    const int j = i % 6;
    const float* __restrict__ p = part + i;        // stride 384 per kblk

    float acc;
    {
        float r[64];
#pragma unroll
        for (int u = 0; u < 64; ++u) r[u] = p[(size_t)u * 384];
        acc = r[0];
#pragma unroll
        for (int u = 1; u < 64; ++u) acc = acc + r[u];
    }
    for (int base = 64; base < 768; base += 64) {
        float r[64];
#pragma unroll
        for (int u = 0; u < 64; ++u) r[u] = p[(size_t)(base + u) * 384];
#pragma unroll
        for (int u = 0; u < 64; ++u) acc = acc + r[u];
    }
    {
        float r[52];
#pragma unroll
        for (int u = 0; u < 52; ++u) r[u] = p[(size_t)(768 + u) * 384];
#pragma unroll
        for (int u = 0; u < 52; ++u) acc = acc + r[u];
    }
    theta[i] = acc + bl[j];
}

// ---------------------------------------------------------------------------
// K2 (round-16, unchanged): bilinear sampler — faithful fp32 numpy replay.
// Float-domain clip via v_med3_f32; divergence-free float2 loads + cndmask.
// ---------------------------------------------------------------------------
__global__ __launch_bounds__(256)
void st_sample(const float* __restrict__ x, const float* __restrict__ theta,
               float* __restrict__ out)
{
#pragma clang fp contract(off)
    __shared__ float th[6];
    const int blk = blockIdx.x;
    const int b   = blk >> 8;          // 256 blocks per batch
    const int rem = blk & 255;
    const int yo  = rem >> 1;
    const int seg = rem & 1;

    if (threadIdx.x < 6) th[threadIdx.x] = theta[b * 6 + threadIdx.x];
    __syncthreads();

    const float t00 = th[0], t01 = th[1], t02 = th[2];
    const float t10 = th[3], t11 = th[4], t12 = th[5];

    const int xo0 = seg * 1024 + threadIdx.x * 4;
    const float* __restrict__ img = x + (size_t)b * HW_;
    const float yof = (float)yo;

    const float cx1 = t01 * yof;
    const float cy1 = t11 * yof;

    nfloat4 o;
#pragma unroll
    for (int i = 0; i < 4; ++i) {
        const float xof = (float)(xo0 + i);
        const float px  = t00 * xof;
        const float sx  = px + cx1;
        const float xq  = sx + t02;
        const float py  = t10 * xof;
        const float sy  = py + cy1;
        const float yq  = sy + t12;

        const float xf0 = floorf(xq);
        const float yf0 = floorf(yq);

        const float x0f = __builtin_amdgcn_fmed3f(xf0,        0.f, 2047.f);
        const float x1f = __builtin_amdgcn_fmed3f(xf0 + 1.0f, 0.f, 2047.f);
        const float y0f = __builtin_amdgcn_fmed3f(yf0,        0.f,  127.f);
        const float y1f = __builtin_amdgcn_fmed3f(yf0 + 1.0f, 0.f,  127.f);

        const float basef = fminf(x0f, 2046.0f);
        const int base_i = (int)basef;
        const int y0c    = (int)y0f;
        const int y1c    = (int)y1f;

        const f2v v0 = *(const f2v*)(img + y0c * W_ + base_i);
        const f2v v1 = *(const f2v*)(img + y1c * W_ + base_i);

        const bool hiA = (x0f == 2047.0f);   // right clamp
        const bool loC = (x1f == basef);     // left clamp
        const float Ia = hiA ? v0.y : v0.x;
        const float Ic = loC ? v0.x : v0.y;
        const float Ib = hiA ? v1.y : v1.x;
        const float Id = loC ? v1.x : v1.y;

        const float gx = x1f - xq;
        const float fx = xq - x0f;
        const float gy = y1f - yq;
        const float fy = yq - y0f;

        const float wa = gx * gy;
        const float wb = gx * fy;
        const float wc = fx * gy;
        const float wd = fx * fy;

        const float pa = wa * Ia;
        const float pb = wb * Ib;
        const float s1 = pa + pb;
        const float pc = wc * Ic;
        const float s2 = s1 + pc;
        const float pd = wd * Id;
        o[i] = s2 + pd;
    }

    const size_t oidx = ((size_t)b * OH_ + yo) * OW_ + xo0;
    __builtin_nontemporal_store(o, (nfloat4*)(out + oidx));
}

extern "C" void kernel_launch(void* const* d_in, const int* in_sizes, int n_in,
                              void* d_out, int out_size, void* d_ws, size_t ws_size,
                              hipStream_t stream)
{
    const float* x  = (const float*)d_in[0];
    const float* w  = (const float*)d_in[1];
    const float* bl = (const float*)d_in[2];
    float* out = (float*)d_out;

    // d_out doubles as the 1.26 MB block-sum scratch (820*384 floats), fully
    // consumed by st_theta_final before st_sample overwrites every element.
    float* part  = (float*)d_out;
    float* theta = (float*)d_ws;    // 384 floats

    st_block_sums<<<NBLK * 2, 192, 0, stream>>>(x, w, part);
    st_theta_final<<<6, 64, 0, stream>>>(part, bl, theta);
    st_sample<<<B_ * OH_ * 2, 256, 0, stream>>>(x, theta, out);
}